// Round 1
// baseline (108.650 us; speedup 1.0000x reference)
//
#include <hip/hip_runtime.h>
#include <stdint.h>

// Problem: B=32, N=512, C=16, D=O=256.  Flattened nodes = 16384.
// K = 768 = 24 slabs of 32: slabs 0..7 = w_t (parent), 8..15 = w_r, 16..23 = w_l.
#define CC 16
#define OO 256
#define NSLAB 24

typedef __attribute__((ext_vector_type(8))) short bf16x8;
typedef __attribute__((ext_vector_type(4))) float f32x4;

__device__ __forceinline__ unsigned short f2bf(float x) {
    unsigned u = __builtin_bit_cast(unsigned, x);
    u += 0x7FFFu + ((u >> 16) & 1u);
    return (unsigned short)(u >> 16);
}

__device__ __forceinline__ uint2 pack_bf4(float4 v) {
    uint2 u;
    u.x = (unsigned)f2bf(v.x) | ((unsigned)f2bf(v.y) << 16);
    u.y = (unsigned)f2bf(v.z) | ((unsigned)f2bf(v.w) << 16);
    return u;
}

// async 16B global -> LDS (wave-uniform LDS base; HW adds lane*16)
__device__ __forceinline__ void cp16(const void* g, void* l) {
    __builtin_amdgcn_global_load_lds(
        (const __attribute__((address_space(1))) unsigned int*)g,
        (__attribute__((address_space(3))) unsigned int*)l, 16, 0, 0);
}

// ---------------------------------------------------------------------------
// Kernel 1: weight prep -> wsb[slab][col][chunk] bf16, with the chunk order
// PRE-PERMUTED (chunk q holds k-chunk q ^ ((col>>1)&3)) so that the GEMM's
// linear global_load_lds staging lands data at XOR-swizzled LDS positions
// (rule #21: inverse-swizzled source + linear dest + swizzled read).
// ---------------------------------------------------------------------------
__global__ __launch_bounds__(256) void wprep(
    const float* __restrict__ wt, const float* __restrict__ wrp,
    const float* __restrict__ wl, unsigned short* __restrict__ wsb) {

    __shared__ __attribute__((aligned(16))) unsigned short T[256 * 40];
    const int slab = blockIdx.x;     // 0..23
    const int n = threadIdx.x;       // col 0..255
#pragma unroll
    for (int kk = 0; kk < 32; ++kk) {
        const int k = slab * 32 + kk;
        const float* s = (k < 256) ? wt : ((k < 512) ? wrp : wl);
        T[n * 40 + kk] = f2bf(s[(k & 255) * OO + n]);
    }
    __syncthreads();
    const int f = (n >> 1) & 3;
    uint4* dst = (uint4*)(wsb + slab * 8192 + n * 32);
    const uint4* src = (const uint4*)&T[n * 40];
#pragma unroll
    for (int q = 0; q < 4; ++q) dst[q] = src[q ^ f];   // involution: read undoes it
}

// ---------------------------------------------------------------------------
// Kernel 2: FUSED gather + GEMM + epilogue.
// 256 blocks (1/CU), 512 threads (8 waves, 2x4 wave grid), 64x256 output tile.
// A-tile (64 rows x 768 k, bf16) built by the gather phase directly in LDS
// (96 KB, XOR-swizzled 16B chunks); B double-buffered 2x16 KB via cp16.
// LDS total = 128 KB. No agg intermediate in global memory.
// ---------------------------------------------------------------------------
__global__ __launch_bounds__(512, 2) void fused_gemm(
    const float* __restrict__ nodes, const int* __restrict__ children,
    const unsigned short* __restrict__ wsb, const float* __restrict__ conv,
    float* __restrict__ out) {

    // As: [slab 24][row 64][k 32] bf16, slab stride 4096 B, chunk-swizzled.
    __shared__ __attribute__((aligned(16))) unsigned short As[NSLAB * 2048];
    // Bs: [buf 2][col 256][k 32] bf16, 16 KB each, chunk-swizzled via wsb order.
    __shared__ __attribute__((aligned(16))) unsigned short Bs[2][8192];

    const int tid  = threadIdx.x;
    const int wave = tid >> 6;
    const int lane = tid & 63;
    const int bid  = blockIdx.x;
    // XCD swizzle: XCD k gets mtiles k*32..k*32+31 = batches 4k..4k+3
    // (2 MB of nodes per XCD L2).  256 blocks, nwg%8==0 -> bijective.
    const int mtile = ((bid & 7) << 5) | (bid >> 3);   // 0..255

    const int toff  = tid * 16;
    const int wbase = (tid & ~63) * 16;                // wave-uniform LDS offset
    const char* wb  = (const char*)wsb;

    auto stageB = [&](int s, int b) {
        cp16(wb + s * 16384 + toff,        (char*)&Bs[b][0] + wbase);
        cp16(wb + s * 16384 + 8192 + toff, (char*)&Bs[b][0] + wbase + 8192);
    };

    stageB(0, 0);   // B slab 0 flies during the gather phase

    // ---------------- gather phase: wave w builds rows w*8 .. w*8+7 ----------
    const int sl    = lane >> 3;          // slab-within-part (k 32-chunk)
    const int l8    = lane & 7;           // k position within slab (x4 floats)
    const int cpb   = l8 >> 1;            // 16B chunk 0..3 within the 64B row
    const int half8 = (lane & 1) * 8;     // 8B half within the chunk
    const float4* g4 = (const float4*)nodes;

    auto reduce_store = [&](int r, const int* cj, float4 pt, const float4* e) {
        int ns = 0;
#pragma unroll
        for (int j = 0; j < CC; ++j) ns += (cj[j] != 0) ? 1 : 0;
        const float inv_den = (ns > 1) ? 1.0f / (float)(ns - 1) : 0.0f;
        const bool single = (ns == 1);
        float4 ar = make_float4(0.f, 0.f, 0.f, 0.f);
        float4 al = make_float4(0.f, 0.f, 0.f, 0.f);
#pragma unroll
        for (int j = 0; j < CC; ++j) {
            const float hasf = (cj[j] != 0) ? 1.0f : 0.0f;
            const float crr  = single ? ((j == 0) ? 0.5f : 0.0f)
                                      : (float)j * inv_den;
            const float cr = crr * hasf;
            const float cl = (1.0f - crr) * hasf;
            ar.x += cr * e[j].x; ar.y += cr * e[j].y;
            ar.z += cr * e[j].z; ar.w += cr * e[j].w;
            al.x += cl * e[j].x; al.y += cl * e[j].y;
            al.z += cl * e[j].z; al.w += cl * e[j].w;
        }
        // swizzled write: chunk' = chunk ^ ((row>>1)&3)
        const int swz = ((cpb ^ ((r >> 1) & 3)) << 4) + half8;
        char* rowb = (char*)As + r * 64 + swz;
        *(uint2*)(rowb + (size_t)(0  + sl) * 4096) = pack_bf4(pt);  // w_t part
        *(uint2*)(rowb + (size_t)(8  + sl) * 4096) = pack_bf4(ar);  // w_r part
        *(uint2*)(rowb + (size_t)(16 + sl) * 4096) = pack_bf4(al);  // w_l part
    };

#pragma unroll 1
    for (int pr = 0; pr < 4; ++pr) {      // 2 nodes per step: 34 loads in flight
        const int r0  = wave * 8 + pr * 2;
        const int nf0 = __builtin_amdgcn_readfirstlane(mtile * 64 + r0);
        const int nf1 = nf0 + 1;
        const int brow = nf0 & ~511;      // batch base row
        const int* ch0 = children + (nf0 << 4);
        const int* ch1 = children + (nf1 << 4);
        int cj0[CC], cj1[CC];
#pragma unroll
        for (int j = 0; j < CC; ++j) cj0[j] = ch0[j];   // scalar (s_load) path
#pragma unroll
        for (int j = 0; j < CC; ++j) cj1[j] = ch1[j];

        // issue ALL vector gathers before any reduction consumes them
        float4 p0 = g4[(size_t)nf0 * 64 + lane];
        float4 p1 = g4[(size_t)nf1 * 64 + lane];
        float4 e0[CC], e1[CC];
#pragma unroll
        for (int j = 0; j < CC; ++j)
            e0[j] = g4[(size_t)(brow + cj0[j]) * 64 + lane];
#pragma unroll
        for (int j = 0; j < CC; ++j)
            e1[j] = g4[(size_t)(brow + cj1[j]) * 64 + lane];

        reduce_store(r0,     cj0, p0, e0);
        reduce_store(r0 + 1, cj1, p1, e1);
    }

    // ---------------- GEMM phase: A resident, B double-buffered --------------
    const int quad = lane >> 4;
    const int l16  = lane & 15;
    const int wrr  = wave >> 2;           // 0..1: 32-row half
    const int wcc  = wave & 3;            // 0..3: 64-col quarter
    const int fx   = ((l16 >> 1) & 3) << 4;   // per-lane swizzle term

    f32x4 acc[2][4];
#pragma unroll
    for (int mi = 0; mi < 2; ++mi)
#pragma unroll
        for (int ni = 0; ni < 4; ++ni)
            acc[mi][ni] = (f32x4){0.f, 0.f, 0.f, 0.f};

#pragma unroll 1
    for (int s = 0; s < NSLAB; ++s) {
        const int cur = s & 1;
        __syncthreads();                  // A ready (s=0) / B[cur] staged, buf free
        if (s + 1 < NSLAB) stageB(s + 1, cur ^ 1);

        bf16x8 af[2], bfr[4];
#pragma unroll
        for (int mi = 0; mi < 2; ++mi)
            af[mi] = *(const bf16x8*)((const char*)As + s * 4096
                        + (wrr * 32 + mi * 16 + l16) * 64 + (((quad << 4)) ^ fx));
#pragma unroll
        for (int ni = 0; ni < 4; ++ni)
            bfr[ni] = *(const bf16x8*)((const char*)&Bs[cur][0]
                        + (wcc * 64 + ni * 16 + l16) * 64 + (((quad << 4)) ^ fx));
#pragma unroll
        for (int mi = 0; mi < 2; ++mi)
#pragma unroll
            for (int ni = 0; ni < 4; ++ni)
                acc[mi][ni] = __builtin_amdgcn_mfma_f32_16x16x32_bf16(
                    af[mi], bfr[ni], acc[mi][ni], 0, 0, 0);
    }

    // ---------------- epilogue: + conv, leaky_relu(0.01), fp32 store ---------
#pragma unroll
    for (int ni = 0; ni < 4; ++ni) {
        const int col = wcc * 64 + ni * 16 + l16;
        const float cv = conv[col];
#pragma unroll
        for (int mi = 0; mi < 2; ++mi) {
#pragma unroll
            for (int r = 0; r < 4; ++r) {
                const int row = mtile * 64 + wrr * 32 + mi * 16 + quad * 4 + r;
                float v = acc[mi][ni][r] + cv;
                v = (v > 0.f) ? v : 0.01f * v;
                out[(size_t)row * OO + col] = v;
            }
        }
    }
}

extern "C" void kernel_launch(void* const* d_in, const int* in_sizes, int n_in,
                              void* d_out, int out_size, void* d_ws, size_t ws_size,
                              hipStream_t stream) {
    // setup_inputs order: nodes, w_t, w_l, w_r, conv, children
    const float* nodes    = (const float*)d_in[0];
    const float* w_t      = (const float*)d_in[1];
    const float* w_l      = (const float*)d_in[2];
    const float* w_r      = (const float*)d_in[3];
    const float* conv     = (const float*)d_in[4];
    const int*   children = (const int*)d_in[5];

    unsigned short* wsb = (unsigned short*)d_ws;      // 393,216 B only

    wprep<<<NSLAB, 256, 0, stream>>>(w_t, w_r, w_l, wsb);
    fused_gemm<<<256, 512, 0, stream>>>(nodes, children, wsb, conv, (float*)d_out);
}

// Round 2
// 104.990 us; speedup vs baseline: 1.0349x; 1.0349x over previous
//
#include <hip/hip_runtime.h>
#include <stdint.h>

// Problem: B=32, N=512, C=16, D=O=256.  Flattened nodes = 16384.
// K = 768 = 12 slabs of 64: slabs 0..3 = w_t, 4..7 = w_r, 8..11 = w_l.
#define CC 16
#define OO 256
#define NSLAB 12
#define SLAB_BYTES (64 * 128)            // 8 KB: 64 rows x 128 B (64 k bf16)
#define MT_BYTES (NSLAB * SLAB_BYTES)    // 98304 B per 64-row mtile
#define AGG_BYTES (256 * MT_BYTES)       // 25,165,824 B
#define NGB 2048                         // gather blocks (8 nodes each)

typedef __attribute__((ext_vector_type(8))) short bf16x8;
typedef __attribute__((ext_vector_type(4))) float f32x4;

__device__ __forceinline__ unsigned short f2bf(float x) {
    unsigned u = __builtin_bit_cast(unsigned, x);
    u += 0x7FFFu + ((u >> 16) & 1u);
    return (unsigned short)(u >> 16);
}

__device__ __forceinline__ uint2 pack_bf4(float4 v) {
    uint2 u;
    u.x = (unsigned)f2bf(v.x) | ((unsigned)f2bf(v.y) << 16);
    u.y = (unsigned)f2bf(v.z) | ((unsigned)f2bf(v.w) << 16);
    return u;
}

// async 16B global -> LDS (wave-uniform LDS base; HW adds lane*16)
__device__ __forceinline__ void cp16(const void* g, void* l) {
    __builtin_amdgcn_global_load_lds(
        (const __attribute__((address_space(1))) unsigned int*)g,
        (__attribute__((address_space(3))) unsigned int*)l, 16, 0, 0);
}

// ---------------------------------------------------------------------------
// Kernel 1: gather + coefficient reduce -> agg (bf16, GEMM staging layout,
// XOR-chunk-swizzled rows) + 12 trailing blocks build wsb (B operand,
// chunk order pre-permuted so linear global_load_lds lands swizzled).
// agg layout: [mtile 256][slab 12][row 64][128 B], chunk c stored at
// position c ^ (row & 7) within the row (16-B chunks).
// No LDS in this kernel -> occupancy limited by VGPR only.
// ---------------------------------------------------------------------------
__global__ __launch_bounds__(256, 4) void gather_prep(
    const float* __restrict__ nodes, const int* __restrict__ children,
    const float* __restrict__ wt, const float* __restrict__ wrp,
    const float* __restrict__ wl, unsigned short* __restrict__ agg,
    unsigned short* __restrict__ wsb) {

    const int p = blockIdx.x;
    const int tid = threadIdx.x;
    char* aggB = (char*)agg;
    char* wsbB = (char*)wsb;

    if (p >= NGB) {
        // ---- weight prep: one block per 64-k slab, no LDS ----
        const int slab = p - NGB;            // 0..11
        const int part = slab >> 2;          // 0 t, 1 r, 2 l
        const int k0 = (slab & 3) * 64;
        const float* W = (part == 0) ? wt : ((part == 1) ? wrp : wl);
        const int n = tid;                   // col 0..255
        const int f = n & 7;                 // read-side XOR term (col&7)
        char* dst = wsbB + slab * 32768 + n * 128;
#pragma unroll
        for (int q = 0; q < 8; ++q) {        // logical 16-B chunk q (8 k each)
            float v[8];
#pragma unroll
            for (int i = 0; i < 8; ++i) v[i] = W[(k0 + q * 8 + i) * OO + n];
            uint4 u;
            u.x = (unsigned)f2bf(v[0]) | ((unsigned)f2bf(v[1]) << 16);
            u.y = (unsigned)f2bf(v[2]) | ((unsigned)f2bf(v[3]) << 16);
            u.z = (unsigned)f2bf(v[4]) | ((unsigned)f2bf(v[5]) << 16);
            u.w = (unsigned)f2bf(v[6]) | ((unsigned)f2bf(v[7]) << 16);
            *(uint4*)(dst + ((q ^ f) << 4)) = u;   // involution: read undoes it
        }
        return;
    }

    // ---- gather: XCD swizzle, XCD k owns batches 4k..4k+3 (L2-resident) ----
    const int wave = tid >> 6;
    const int lane = tid & 63;
    const int lb = (p & 7) * 256 + (p >> 3);
    const int base = lb * 8;                 // 8 nodes per block, 2 per wave
    const float4* g4 = (const float4*)nodes;

    // store-side decomposition: lane covers k = part*256 + lane*4 .. +4
    const int s4  = lane >> 4;               // slab-within-part (64-k group)
    const int chk = (lane & 15) >> 1;        // 16-B chunk 0..7 within row
    const int hb  = (lane & 1) * 8;          // 8-B half within chunk

#pragma unroll 1
    for (int i = 0; i < 2; ++i) {
        const int nf = __builtin_amdgcn_readfirstlane(base + wave * 2 + i);
        const int brow = nf & ~511;          // b*512
        const int* chp = children + (nf << 4);
        int cj[CC];
#pragma unroll
        for (int j = 0; j < CC; ++j) cj[j] = chp[j];   // scalar loads (SGPR)
        int ns = 0;
#pragma unroll
        for (int j = 0; j < CC; ++j) ns += (cj[j] != 0) ? 1 : 0;
        const float inv_den = (ns > 1) ? 1.0f / (float)(ns - 1) : 0.0f;
        const bool single = (ns == 1);

        // ---- issue ALL gathers first (17 loads in flight) ----
        float4 pt = g4[(size_t)nf * 64 + lane];
        float4 e[CC];
#pragma unroll
        for (int j = 0; j < CC; ++j)
            e[j] = g4[(size_t)(brow + cj[j]) * 64 + lane];

        // ---- reduce with reference _coefs (branchless mask) ----
        float4 ar = make_float4(0.f, 0.f, 0.f, 0.f);
        float4 al = make_float4(0.f, 0.f, 0.f, 0.f);
#pragma unroll
        for (int j = 0; j < CC; ++j) {
            const float hasf = (cj[j] != 0) ? 1.0f : 0.0f;
            const float crr  = single ? ((j == 0) ? 0.5f : 0.0f)
                                      : (float)j * inv_den;
            const float cr = crr * hasf;
            const float cl = (1.0f - crr) * hasf;
            ar.x += cr * e[j].x; ar.y += cr * e[j].y;
            ar.z += cr * e[j].z; ar.w += cr * e[j].w;
            al.x += cl * e[j].x; al.y += cl * e[j].y;
            al.z += cl * e[j].z; al.w += cl * e[j].w;
        }

        // ---- swizzled store: chunk' = chunk ^ (row & 7) ----
        const int row = nf & 63;
        char* rowb = aggB + (size_t)(nf >> 6) * MT_BYTES + row * 128
                   + ((chk ^ (row & 7)) << 4) + hb;
        *(uint2*)(rowb + (size_t)(0 + s4) * SLAB_BYTES) = pack_bf4(pt);  // w_t
        *(uint2*)(rowb + (size_t)(4 + s4) * SLAB_BYTES) = pack_bf4(ar);  // w_r
        *(uint2*)(rowb + (size_t)(8 + s4) * SLAB_BYTES) = pack_bf4(al);  // w_l
    }
}

// ---------------------------------------------------------------------------
// Kernel 2: GEMM (16384 x 768) x (768 x 256) + bias + leaky_relu -> out fp32
// 64x128 tile, 512 blocks (2/CU), BK=64 (12 phases), dbuf LDS (48 KB),
// global_load_lds staging, 2-way-free swizzled fragment reads.
// XCD map matches gather's: agg written/read within the same XCD L2.
// ---------------------------------------------------------------------------
__global__ __launch_bounds__(256, 2) void gemm_ep(
    const unsigned short* __restrict__ agg, const unsigned short* __restrict__ wsb,
    const float* __restrict__ conv, float* __restrict__ out) {

    __shared__ __attribute__((aligned(16))) unsigned short Ab[2][4096]; // 2x8 KB
    __shared__ __attribute__((aligned(16))) unsigned short Bb[2][8192]; // 2x16 KB

    const int tid  = threadIdx.x;
    const int wave = tid >> 6;
    const int lane = tid & 63;
    const int quad = lane >> 4;
    const int l16  = lane & 15;
    const int bid  = blockIdx.x;
    const int lb = (bid & 7) * 64 + (bid >> 3);   // XCD k -> tiles k*64..
    const int mtile = lb >> 1;                     // 0..255
    const int ntile = lb & 1;                      // 0..1
    const int wrr = wave >> 1;                     // M half (32 rows)
    const int wcc = wave & 1;                      // N half (64 cols)

    const char* aggb = (const char*)agg + (size_t)mtile * MT_BYTES;
    const char* wsbb = (const char*)wsb + ntile * 16384;
    const int toff  = tid * 16;
    const int wbase = (tid & ~63) * 16;            // wave-uniform LDS offset

    f32x4 acc[2][4];
#pragma unroll
    for (int mi = 0; mi < 2; ++mi)
#pragma unroll
        for (int ni = 0; ni < 4; ++ni)
            acc[mi][ni] = (f32x4){0.f, 0.f, 0.f, 0.f};

    auto stage = [&](int s, int b) {
        const char* ga = aggb + s * SLAB_BYTES + toff;       // 8 KB A slab
        cp16(ga,        (char*)&Ab[b][0] + wbase);
        cp16(ga + 4096, (char*)&Ab[b][0] + wbase + 4096);
        const char* gb = wsbb + s * 32768 + toff;            // 16 KB B slab
        cp16(gb,         (char*)&Bb[b][0] + wbase);
        cp16(gb + 4096,  (char*)&Bb[b][0] + wbase + 4096);
        cp16(gb + 8192,  (char*)&Bb[b][0] + wbase + 8192);
        cp16(gb + 12288, (char*)&Bb[b][0] + wbase + 12288);
    };

    stage(0, 0);
    const int fx = l16 & 7;     // == row&7 == col&7 for this lane's fragments

#pragma unroll 1
    for (int s = 0; s < NSLAB; ++s) {
        const int cur = s & 1;
        __syncthreads();                  // slab s staged (vmcnt drain)
        if (s + 1 < NSLAB) stage(s + 1, cur ^ 1);   // async prefetch

        bf16x8 af[2][2], bfr[2][4];
#pragma unroll
        for (int h = 0; h < 2; ++h) {
            const int co = (((h * 4 + quad) ^ fx) << 4);   // swizzled chunk
#pragma unroll
            for (int mi = 0; mi < 2; ++mi)
                af[h][mi] = *(const bf16x8*)((const char*)&Ab[cur][0]
                            + (wrr * 32 + mi * 16 + l16) * 128 + co);
#pragma unroll
            for (int ni = 0; ni < 4; ++ni)
                bfr[h][ni] = *(const bf16x8*)((const char*)&Bb[cur][0]
                            + (wcc * 64 + ni * 16 + l16) * 128 + co);
        }
#pragma unroll
        for (int h = 0; h < 2; ++h)
#pragma unroll
            for (int mi = 0; mi < 2; ++mi)
#pragma unroll
                for (int ni = 0; ni < 4; ++ni)
                    acc[mi][ni] = __builtin_amdgcn_mfma_f32_16x16x32_bf16(
                        af[h][mi], bfr[h][ni], acc[mi][ni], 0, 0, 0);
    }

    // epilogue: + conv, leaky_relu(0.01), fp32 store
#pragma unroll
    for (int ni = 0; ni < 4; ++ni) {
        const int col = ntile * 128 + wcc * 64 + ni * 16 + l16;
        const float cv = conv[col];
#pragma unroll
        for (int mi = 0; mi < 2; ++mi) {
#pragma unroll
            for (int r = 0; r < 4; ++r) {
                const int row = mtile * 64 + wrr * 32 + mi * 16 + quad * 4 + r;
                float v = acc[mi][ni][r] + cv;
                v = (v > 0.f) ? v : 0.01f * v;
                out[(size_t)row * OO + col] = v;
            }
        }
    }
}

extern "C" void kernel_launch(void* const* d_in, const int* in_sizes, int n_in,
                              void* d_out, int out_size, void* d_ws, size_t ws_size,
                              hipStream_t stream) {
    // setup_inputs order: nodes, w_t, w_l, w_r, conv, children
    const float* nodes    = (const float*)d_in[0];
    const float* w_t      = (const float*)d_in[1];
    const float* w_l      = (const float*)d_in[2];
    const float* w_r      = (const float*)d_in[3];
    const float* conv     = (const float*)d_in[4];
    const int*   children = (const int*)d_in[5];

    unsigned short* agg = (unsigned short*)d_ws;                    // 25.2 MB
    unsigned short* wsb = (unsigned short*)((char*)d_ws + AGG_BYTES); // +384 KB

    gather_prep<<<NGB + NSLAB, 256, 0, stream>>>(nodes, children, w_t, w_r, w_l,
                                                 agg, wsb);
    gemm_ep<<<512, 256, 0, stream>>>(agg, wsb, conv, (float*)d_out);
}